// Round 1
// baseline (590.688 us; speedup 1.0000x reference)
//
#include <hip/hip_runtime.h>
#include <math.h>

#define NUM_HOP 3
#define VOCAB   32000
#define DIM     512
#define MEM     60
#define BS      64
#define STORY   50
#define SENT    32
#define QLEN    16

// ---------------------------------------------------------------------------
// u[b,:] = sum_t A0[query[b,t]]  (padding idx 0 -> zero row)
// grid: BS blocks, 128 threads; thread owns 4 consecutive d
__global__ void k_query(const float* __restrict__ A0,
                        const int*   __restrict__ query,
                        float*       __restrict__ u) {
    const int b = blockIdx.x;
    const int d = threadIdx.x * 4;
    const int* q = query + b * QLEN;
    float4 acc = make_float4(0.f, 0.f, 0.f, 0.f);
    for (int t = 0; t < QLEN; ++t) {
        const int idx = q[t];
        if (idx != 0) {
            const float4 a = *(const float4*)(A0 + (size_t)idx * DIM + d);
            acc.x += a.x; acc.y += a.y; acc.z += a.z; acc.w += a.w;
        }
    }
    *(float4*)(u + (size_t)b * DIM + d) = acc;
}

// ---------------------------------------------------------------------------
// One gather pass over `table` with the context indices.
// Produces (optionally) mw[bs,:] = sum_w table[ctx[bs,w]] * pe[w,:]
// and      (optionally) c [bs,:] = sum_w table[ctx[bs,w]]
// grid: BS*STORY blocks, 128 threads; thread owns 4 consecutive d
__global__ void k_pass(const float* __restrict__ table,
                       const int*   __restrict__ ctx,
                       float*       __restrict__ mw,
                       float*       __restrict__ c,
                       int write_mw, int write_c) {
    const int bs  = blockIdx.x;
    const int d   = threadIdx.x * 4;
    const int* cw = ctx + bs * SENT;
    float4 m  = make_float4(0.f, 0.f, 0.f, 0.f);
    float4 cc = make_float4(0.f, 0.f, 0.f, 0.f);
    const float invD = 1.0f / (float)DIM;
    #pragma unroll 4
    for (int w = 0; w < SENT; ++w) {
        const int idx = cw[w];
        if (idx == 0) continue;
        const float4 a = *(const float4*)(table + (size_t)idx * DIM + d);
        // pe[w,k] = aw - bw*(k+1)/D,  aw = 1-(w+1)/SENT, bw = 1-2*(w+1)/SENT
        const float aw = 1.0f - (float)(w + 1) * (1.0f / (float)SENT);
        const float bw = 1.0f - (float)(2 * (w + 1)) * (1.0f / (float)SENT);
        const float p0 = aw - bw * (float)(d + 1) * invD;
        const float p1 = aw - bw * (float)(d + 2) * invD;
        const float p2 = aw - bw * (float)(d + 3) * invD;
        const float p3 = aw - bw * (float)(d + 4) * invD;
        m.x = fmaf(a.x, p0, m.x);
        m.y = fmaf(a.y, p1, m.y);
        m.z = fmaf(a.z, p2, m.z);
        m.w = fmaf(a.w, p3, m.w);
        cc.x += a.x; cc.y += a.y; cc.z += a.z; cc.w += a.w;
    }
    if (write_mw) *(float4*)(mw + (size_t)bs * DIM + d) = m;
    if (write_c)  *(float4*)(c  + (size_t)bs * DIM + d) = cc;
}

// ---------------------------------------------------------------------------
// scores[bs] = dot(mw[bs,:] + T_A[s,:], u[b,:])
// grid: BS*STORY blocks, 128 threads
__global__ void k_score(const float* __restrict__ mw,
                        const float* __restrict__ T_A,
                        const float* __restrict__ u,
                        float*       __restrict__ scores) {
    const int bs = blockIdx.x;
    const int b  = bs / STORY;
    const int s  = bs % STORY;
    const int tid = threadIdx.x;
    const int d   = tid * 4;
    const float4 m  = *(const float4*)(mw  + (size_t)bs * DIM + d);
    const float4 t  = *(const float4*)(T_A + (size_t)s  * DIM + d);
    const float4 uu = *(const float4*)(u   + (size_t)b  * DIM + d);
    float part = (m.x + t.x) * uu.x + (m.y + t.y) * uu.y +
                 (m.z + t.z) * uu.z + (m.w + t.w) * uu.w;
    for (int off = 32; off; off >>= 1) part += __shfl_down(part, off);
    __shared__ float wred[2];
    if ((tid & 63) == 0) wred[tid >> 6] = part;
    __syncthreads();
    if (tid == 0) scores[bs] = wred[0] + wred[1];
}

// ---------------------------------------------------------------------------
// p = softmax(scores[b,:]) over STORY; u[b,:] += sum_s p[s]*c[b,s,:]
// grid: BS blocks, 128 threads
__global__ void k_update(const float* __restrict__ scores,
                         const float* __restrict__ c,
                         float*       __restrict__ u) {
    const int b   = blockIdx.x;
    const int tid = threadIdx.x;
    __shared__ float sp[STORY];
    __shared__ float se[STORY];
    if (tid < STORY) sp[tid] = scores[b * STORY + tid];
    __syncthreads();
    float mx = -1e30f;
    for (int s = 0; s < STORY; ++s) mx = fmaxf(mx, sp[s]);
    __syncthreads();
    if (tid < STORY) se[tid] = expf(sp[tid] - mx);
    __syncthreads();
    float sum = 0.f;
    for (int s = 0; s < STORY; ++s) sum += se[s];
    const float inv = 1.0f / sum;
    const int d = tid * 4;
    float4 acc = *(float4*)(u + (size_t)b * DIM + d);
    for (int s = 0; s < STORY; ++s) {
        const float w = se[s] * inv;
        const float4 c4 = *(const float4*)(c + ((size_t)(b * STORY + s)) * DIM + d);
        acc.x = fmaf(w, c4.x, acc.x);
        acc.y = fmaf(w, c4.y, acc.y);
        acc.z = fmaf(w, c4.z, acc.z);
        acc.w = fmaf(w, c4.w, acc.w);
    }
    *(float4*)(u + (size_t)b * DIM + d) = acc;
}

// ---------------------------------------------------------------------------
// logits[b,v] = dot(u[b,:], A3[v,:])  written into d_out
// grid: (63, 4); block 256 threads. blockIdx.y picks group of 16 b's (LDS),
// each thread streams 2 contiguous A3 rows.
__global__ void k_logits(const float* __restrict__ A3,
                         const float* __restrict__ u,
                         float*       __restrict__ out) {
    __shared__ float Ub[16 * DIM];  // 32 KB
    const int tid = threadIdx.x;
    const int bg  = blockIdx.y;
    for (int i = tid; i < 16 * DIM; i += 256) Ub[i] = u[(size_t)bg * 16 * DIM + i];
    __syncthreads();
    const int v = blockIdx.x * 512 + tid * 2;
    if (v >= VOCAB) return;
    const float* r0 = A3 + (size_t)v * DIM;
    const float* r1 = r0 + DIM;
    float acc0[16], acc1[16];
    #pragma unroll
    for (int bb = 0; bb < 16; ++bb) { acc0[bb] = 0.f; acc1[bb] = 0.f; }
    for (int k = 0; k < DIM; k += 4) {
        const float4 a0 = *(const float4*)(r0 + k);
        const float4 a1 = *(const float4*)(r1 + k);
        #pragma unroll
        for (int bb = 0; bb < 16; ++bb) {
            const float4 ub = *(const float4*)(&Ub[bb * DIM + k]);  // broadcast
            acc0[bb] = fmaf(a0.x, ub.x, fmaf(a0.y, ub.y, fmaf(a0.z, ub.z, fmaf(a0.w, ub.w, acc0[bb]))));
            acc1[bb] = fmaf(a1.x, ub.x, fmaf(a1.y, ub.y, fmaf(a1.z, ub.z, fmaf(a1.w, ub.w, acc1[bb]))));
        }
    }
    #pragma unroll
    for (int bb = 0; bb < 16; ++bb) {
        float2 st = make_float2(acc0[bb], acc1[bb]);
        *(float2*)(out + (size_t)(bg * 16 + bb) * VOCAB + v) = st;
    }
}

// ---------------------------------------------------------------------------
// in-place row softmax over VOCAB. grid: BS blocks, 256 threads
__global__ void k_vsm(float* __restrict__ out) {
    const int b = blockIdx.x;
    float* row = out + (size_t)b * VOCAB;
    const int tid = threadIdx.x;
    __shared__ float red[256];
    float mx = -1e30f;
    for (int v = tid; v < VOCAB; v += 256) mx = fmaxf(mx, row[v]);
    red[tid] = mx; __syncthreads();
    for (int off = 128; off; off >>= 1) {
        if (tid < off) red[tid] = fmaxf(red[tid], red[tid + off]);
        __syncthreads();
    }
    mx = red[0]; __syncthreads();
    float sum = 0.f;
    for (int v = tid; v < VOCAB; v += 256) sum += expf(row[v] - mx);
    red[tid] = sum; __syncthreads();
    for (int off = 128; off; off >>= 1) {
        if (tid < off) red[tid] += red[tid + off];
        __syncthreads();
    }
    const float inv = 1.0f / red[0];
    for (int v = tid; v < VOCAB; v += 256) row[v] = expf(row[v] - mx) * inv;
}

// ---------------------------------------------------------------------------
extern "C" void kernel_launch(void* const* d_in, const int* in_sizes, int n_in,
                              void* d_out, int out_size, void* d_ws, size_t ws_size,
                              hipStream_t stream) {
    const int*   ctx   = (const int*)d_in[0];    // (BS, STORY, SENT)
    const int*   query = (const int*)d_in[1];    // (BS, QLEN)
    const float* A     = (const float*)d_in[2];  // (4, VOCAB, DIM)
    const float* T_A   = (const float*)d_in[3];  // (1, MEM, DIM)
    float* out = (float*)d_out;                  // (BS, VOCAB)

    // workspace layout (floats)
    float* u      = (float*)d_ws;                      // BS*DIM          = 32768
    float* scores = u + (size_t)BS * DIM;              // BS*STORY        = 3200
    float* mw     = scores + (size_t)BS * STORY;       // BS*STORY*DIM    = 1638400
    float* c      = mw + (size_t)BS * STORY * DIM;     // BS*STORY*DIM    = 1638400

    const size_t TBL = (size_t)VOCAB * DIM;

    // u0 and pe-weighted memory for hop 0 (table A0)
    k_query<<<BS, 128, 0, stream>>>(A, query, u);
    k_pass <<<BS * STORY, 128, 0, stream>>>(A, ctx, mw, c, 1, 0);

    for (int h = 0; h < NUM_HOP; ++h) {
        // scores_h from mw (A[h]-weighted) + T_A vs current u
        k_score<<<BS * STORY, 128, 0, stream>>>(mw, T_A, u, scores);
        // single gather pass over A[h+1]: c_h (unweighted) and mw_{h+1} (weighted)
        const int need_mw = (h < NUM_HOP - 1) ? 1 : 0;
        k_pass<<<BS * STORY, 128, 0, stream>>>(A + (size_t)(h + 1) * TBL, ctx,
                                               mw, c, need_mw, 1);
        // u += p @ c
        k_update<<<BS, 128, 0, stream>>>(scores, c, u);
    }

    // logits = u @ A3^T, then row softmax, both on d_out
    k_logits<<<dim3(63, 4), 256, 0, stream>>>(A + (size_t)NUM_HOP * TBL, u, out);
    k_vsm   <<<BS, 256, 0, stream>>>(out);
}

// Round 2
// 528.344 us; speedup vs baseline: 1.1180x; 1.1180x over previous
//
#include <hip/hip_runtime.h>
#include <math.h>

#define NUM_HOP 3
#define VOCAB   32000
#define DIM     512
#define MEM     60
#define BS      64
#define STORY   50
#define SENT    32
#define QLEN    16

typedef short v8s __attribute__((ext_vector_type(8)));   // 8 bf16 (guide §3)
typedef float v4f __attribute__((ext_vector_type(4)));

static __device__ __forceinline__ ushort f2bf(float x) {
    union { float f; unsigned u; } v; v.f = x;
    unsigned r = (v.u + 0x7FFFu + ((v.u >> 16) & 1u)) >> 16;
    return (ushort)r;
}

// ---------------------------------------------------------------------------
// Gather pass over one table. blocks [0, BS*STORY): per (b,s) sentence,
//   mw[bs,:] = sum_w table[ctx]*pe   (if write_mw)
//   c [bs,:] = sum_w table[ctx]      (if write_c)
// blocks [BS*STORY, +BS) when do_query: u[b,:] = sum_t table[query[b,t]]
__global__ void k_pass(const float* __restrict__ table,
                       const int*   __restrict__ ctx,
                       const int*   __restrict__ query,
                       float*       __restrict__ mw,
                       float*       __restrict__ c,
                       float*       __restrict__ u,
                       int write_mw, int write_c, int do_query) {
    const int blk = blockIdx.x;
    const int d   = threadIdx.x * 4;
    if (do_query && blk >= BS * STORY) {
        const int b = blk - BS * STORY;
        const int* q = query + b * QLEN;
        float4 acc = make_float4(0.f, 0.f, 0.f, 0.f);
        for (int t = 0; t < QLEN; ++t) {
            const int idx = q[t];
            if (idx != 0) {
                const float4 a = *(const float4*)(table + (size_t)idx * DIM + d);
                acc.x += a.x; acc.y += a.y; acc.z += a.z; acc.w += a.w;
            }
        }
        *(float4*)(u + (size_t)b * DIM + d) = acc;
        return;
    }
    const int* cw = ctx + blk * SENT;
    float4 m  = make_float4(0.f, 0.f, 0.f, 0.f);
    float4 cc = make_float4(0.f, 0.f, 0.f, 0.f);
    const float invD = 1.0f / (float)DIM;
    #pragma unroll 8
    for (int w = 0; w < SENT; ++w) {
        const int idx = cw[w];
        if (idx == 0) continue;
        const float4 a = *(const float4*)(table + (size_t)idx * DIM + d);
        const float aw = 1.0f - (float)(w + 1) * (1.0f / (float)SENT);
        const float bw = 1.0f - (float)(2 * (w + 1)) * (1.0f / (float)SENT);
        const float p0 = aw - bw * (float)(d + 1) * invD;
        const float p1 = aw - bw * (float)(d + 2) * invD;
        const float p2 = aw - bw * (float)(d + 3) * invD;
        const float p3 = aw - bw * (float)(d + 4) * invD;
        m.x = fmaf(a.x, p0, m.x);
        m.y = fmaf(a.y, p1, m.y);
        m.z = fmaf(a.z, p2, m.z);
        m.w = fmaf(a.w, p3, m.w);
        cc.x += a.x; cc.y += a.y; cc.z += a.z; cc.w += a.w;
    }
    if (write_mw) *(float4*)(mw + (size_t)blk * DIM + d) = m;
    if (write_c)  *(float4*)(c  + (size_t)blk * DIM + d) = cc;
}

// ---------------------------------------------------------------------------
// One hop fused: scores = (mw + T_A) . u -> softmax over STORY -> u += p @ c
// grid: BS blocks, 256 threads (4 waves). If ubf != null, also emit bf16 u.
__global__ __launch_bounds__(256) void k_hop(const float* __restrict__ mw,
                                             const float* __restrict__ c,
                                             const float* __restrict__ T_A,
                                             float*       __restrict__ u,
                                             ushort*      __restrict__ ubf) {
    const int b    = blockIdx.x;
    const int tid  = threadIdx.x;
    const int wave = tid >> 6;
    const int lane = tid & 63;
    __shared__ float sw[64];

    const float* ub = u + (size_t)b * DIM;
    // u cached in regs: lane owns 8 consecutive dims
    const float4 u0 = *(const float4*)(ub + lane * 8);
    const float4 u1 = *(const float4*)(ub + lane * 8 + 4);

    // Phase A: scores (wave w handles stories w, w+4, ...)
    for (int s = wave; s < STORY; s += 4) {
        const float* mrow = mw  + ((size_t)b * STORY + s) * DIM + lane * 8;
        const float* trow = T_A + (size_t)s * DIM + lane * 8;
        const float4 m0 = *(const float4*)(mrow);
        const float4 m1 = *(const float4*)(mrow + 4);
        const float4 t0 = *(const float4*)(trow);
        const float4 t1 = *(const float4*)(trow + 4);
        float p = (m0.x + t0.x) * u0.x + (m0.y + t0.y) * u0.y +
                  (m0.z + t0.z) * u0.z + (m0.w + t0.w) * u0.w +
                  (m1.x + t1.x) * u1.x + (m1.y + t1.y) * u1.y +
                  (m1.z + t1.z) * u1.z + (m1.w + t1.w) * u1.w;
        for (int off = 32; off; off >>= 1) p += __shfl_down(p, off);
        if (lane == 0) sw[s] = p;
    }
    __syncthreads();

    // Phase B: softmax over STORY (wave 0 only)
    if (tid < 64) {
        const float v = (tid < STORY) ? sw[tid] : -1e30f;
        float mx = v;
        for (int off = 32; off; off >>= 1) mx = fmaxf(mx, __shfl_down(mx, off));
        mx = __shfl(mx, 0);
        const float e = (tid < STORY) ? __expf(v - mx) : 0.f;
        float sm = e;
        for (int off = 32; off; off >>= 1) sm += __shfl_down(sm, off);
        sm = __shfl(sm, 0);
        if (tid < STORY) sw[tid] = e / sm;
    }
    __syncthreads();

    // Phase C: u += p @ c  (thread owns 2 dims)
    const int d = tid * 2;
    float2 acc = *(const float2*)(ub + d);
    const float* crow = c + (size_t)b * STORY * DIM + d;
    #pragma unroll 5
    for (int s = 0; s < STORY; ++s) {
        const float  w  = sw[s];
        const float2 cc = *(const float2*)(crow + (size_t)s * DIM);
        acc.x = fmaf(w, cc.x, acc.x);
        acc.y = fmaf(w, cc.y, acc.y);
    }
    *(float2*)(u + (size_t)b * DIM + d) = acc;
    if (ubf) {
        ubf[b * DIM + d]     = f2bf(acc.x);
        ubf[b * DIM + d + 1] = f2bf(acc.y);
    }
}

// ---------------------------------------------------------------------------
// logits = u @ A3^T via bf16 MFMA 16x16x32. M=32000 rows (A3), N=64 (batch),
// K=512. Per block: 64 contiguous rows, K in 4 chunks of 128. A3 read ONCE.
// LDS layout: [row][g] g = 8-bf16 group, XOR-swizzled (g ^ (row&7)) so the
// 16 fragment lanes (1 KB-ish stride) spread across banks.
__global__ __launch_bounds__(256) void k_logits(const float*  __restrict__ A3,
                                                const ushort* __restrict__ ubf,
                                                float*        __restrict__ out) {
    __shared__ ushort Abf[64 * 128];  // 16 KB
    __shared__ ushort Ubf[64 * 128];  // 16 KB
    const int tid  = threadIdx.x;
    const int lane = tid & 63;
    const int wave = tid >> 6;
    const int i16  = lane & 15;
    const int quad = lane >> 4;
    const int row0 = blockIdx.x * 64;

    v4f acc[4];
    #pragma unroll
    for (int nt = 0; nt < 4; ++nt) acc[nt] = (v4f){0.f, 0.f, 0.f, 0.f};

    for (int ko = 0; ko < 4; ++ko) {
        __syncthreads();
        // stage A3 chunk: 64 rows x 16 groups of 8 floats -> bf16
        #pragma unroll
        for (int it = 0; it < 4; ++it) {
            const int i = it * 256 + tid;      // 0..1023
            const int r = i >> 4, g = i & 15;
            const float* src = A3 + ((size_t)(row0 + r)) * DIM + ko * 128 + g * 8;
            const float4 f0 = *(const float4*)(src);
            const float4 f1 = *(const float4*)(src + 4);
            union { ushort h[8]; uint4 q; } pk;
            pk.h[0] = f2bf(f0.x); pk.h[1] = f2bf(f0.y);
            pk.h[2] = f2bf(f0.z); pk.h[3] = f2bf(f0.w);
            pk.h[4] = f2bf(f1.x); pk.h[5] = f2bf(f1.y);
            pk.h[6] = f2bf(f1.z); pk.h[7] = f2bf(f1.w);
            *(uint4*)(&Abf[r * 128 + ((g ^ (r & 7)) * 8)]) = pk.q;
        }
        // stage u chunk (already bf16 in global)
        #pragma unroll
        for (int it = 0; it < 4; ++it) {
            const int i = it * 256 + tid;
            const int n = i >> 4, g = i & 15;
            const uint4 v = *(const uint4*)(ubf + (size_t)n * DIM + ko * 128 + g * 8);
            *(uint4*)(&Ubf[n * 128 + ((g ^ (n & 7)) * 8)]) = v;
        }
        __syncthreads();

        const int arow = wave * 16 + i16;
        #pragma unroll
        for (int ki = 0; ki < 4; ++ki) {
            const int ga = ki * 4 + quad;
            const v8s a = *(const v8s*)(&Abf[arow * 128 + ((ga ^ (arow & 7)) * 8)]);
            #pragma unroll
            for (int nt = 0; nt < 4; ++nt) {
                const int n = nt * 16 + i16;
                const v8s bb = *(const v8s*)(&Ubf[n * 128 + ((ga ^ (n & 7)) * 8)]);
                acc[nt] = __builtin_amdgcn_mfma_f32_16x16x32_bf16(a, bb, acc[nt], 0, 0, 0);
            }
        }
    }

    // C/D: col = lane&15 -> batch, row = quad*4 + reg -> vocab row
    const int vbase = row0 + wave * 16 + quad * 4;
    #pragma unroll
    for (int nt = 0; nt < 4; ++nt) {
        const int bcol = nt * 16 + i16;
        #pragma unroll
        for (int r = 0; r < 4; ++r)
            out[(size_t)bcol * VOCAB + vbase + r] = acc[nt][r];
    }
}

// ---------------------------------------------------------------------------
// in-place row softmax over VOCAB. grid: BS blocks, 256 threads
__global__ void k_vsm(float* __restrict__ out) {
    const int b = blockIdx.x;
    float* row = out + (size_t)b * VOCAB;
    const int tid = threadIdx.x;
    __shared__ float red[256];
    float mx = -1e30f;
    for (int v = tid; v < VOCAB; v += 256) mx = fmaxf(mx, row[v]);
    red[tid] = mx; __syncthreads();
    for (int off = 128; off; off >>= 1) {
        if (tid < off) red[tid] = fmaxf(red[tid], red[tid + off]);
        __syncthreads();
    }
    mx = red[0]; __syncthreads();
    float sum = 0.f;
    for (int v = tid; v < VOCAB; v += 256) sum += __expf(row[v] - mx);
    red[tid] = sum; __syncthreads();
    for (int off = 128; off; off >>= 1) {
        if (tid < off) red[tid] += red[tid + off];
        __syncthreads();
    }
    const float inv = 1.0f / red[0];
    for (int v = tid; v < VOCAB; v += 256) row[v] = __expf(row[v] - mx) * inv;
}

// ---------------------------------------------------------------------------
extern "C" void kernel_launch(void* const* d_in, const int* in_sizes, int n_in,
                              void* d_out, int out_size, void* d_ws, size_t ws_size,
                              hipStream_t stream) {
    const int*   ctx   = (const int*)d_in[0];    // (BS, STORY, SENT)
    const int*   query = (const int*)d_in[1];    // (BS, QLEN)
    const float* A     = (const float*)d_in[2];  // (4, VOCAB, DIM)
    const float* T_A   = (const float*)d_in[3];  // (1, MEM, DIM)
    float* out = (float*)d_out;                  // (BS, VOCAB)

    // workspace layout
    float*  u   = (float*)d_ws;                        // BS*DIM floats
    ushort* ubf = (ushort*)(u + (size_t)BS * DIM);     // BS*DIM bf16
    float*  buf = (float*)(ubf + (size_t)BS * DIM);
    const size_t SZ = (size_t)BS * STORY * DIM;
    float* mw0 = buf;
    float* mw1 = mw0 + SZ;
    float* mw2 = mw1 + SZ;
    float* c0  = mw2 + SZ;
    float* c1  = c0 + SZ;
    float* c2  = c1 + SZ;

    const size_t TBL = (size_t)VOCAB * DIM;

    // gather passes (one per table; table working set stays L3-resident)
    k_pass<<<BS * STORY + BS, 128, 0, stream>>>(A,           ctx, query, mw0, nullptr, u, 1, 0, 1);
    k_pass<<<BS * STORY,      128, 0, stream>>>(A + TBL,     ctx, query, mw1, c0,      u, 1, 1, 0);
    k_pass<<<BS * STORY,      128, 0, stream>>>(A + 2 * TBL, ctx, query, mw2, c1,      u, 1, 1, 0);
    k_pass<<<BS * STORY,      128, 0, stream>>>(A + 3 * TBL, ctx, query, nullptr, c2,  u, 0, 1, 0);

    // hops (score + softmax + update fused); last hop also emits bf16 u
    k_hop<<<BS, 256, 0, stream>>>(mw0, c0, T_A, u, nullptr);
    k_hop<<<BS, 256, 0, stream>>>(mw1, c1, T_A, u, nullptr);
    k_hop<<<BS, 256, 0, stream>>>(mw2, c2, T_A, u, ubf);

    // logits via bf16 MFMA (A3 read once), then vocab softmax
    k_logits<<<VOCAB / 64, 256, 0, stream>>>(A + 3 * TBL, ubf, out);
    k_vsm   <<<BS, 256, 0, stream>>>(out);
}

// Round 3
// 455.580 us; speedup vs baseline: 1.2966x; 1.1597x over previous
//
#include <hip/hip_runtime.h>
#include <math.h>

#define NUM_HOP 3
#define VOCAB   32000
#define DIM     512
#define MEM     60
#define BS      64
#define STORY   50
#define SENT    32
#define QLEN    16

#define SZ      ((size_t)BS * STORY * DIM)
#define TBL     ((size_t)VOCAB * DIM)

typedef short v8s __attribute__((ext_vector_type(8)));   // 8 bf16
typedef float v4f __attribute__((ext_vector_type(4)));

static __device__ __forceinline__ ushort f2bf(float x) {
    union { float f; unsigned u; } v; v.f = x;
    unsigned r = (v.u + 0x7FFFu + ((v.u >> 16) & 1u)) >> 16;
    return (ushort)r;
}

// ---------------------------------------------------------------------------
// ALL gather work in one launch.
// blocks [0, 4*BS*STORY): pass p = blk/3200 over table A[p], sentence bs.
//   p<3  -> mw[p][bs,:] = sum_w A[p][ctx]*pe
//   p>0  -> c[p-1][bs,:] = sum_w A[p][ctx]
// blocks [4*BS*STORY, +BS): u[b,:] = sum_t A[0][query[b,t]]
__global__ __launch_bounds__(128) void k_gather(const float* __restrict__ A,
                                                const int*   __restrict__ ctx,
                                                const int*   __restrict__ query,
                                                float*       __restrict__ mw,
                                                float*       __restrict__ c,
                                                float*       __restrict__ u) {
    const unsigned blk = blockIdx.x;
    const int d = threadIdx.x * 4;
    if (blk >= 4u * BS * STORY) {
        const int b = blk - 4u * BS * STORY;
        const int* q = query + b * QLEN;
        float4 acc = make_float4(0.f, 0.f, 0.f, 0.f);
        for (int t = 0; t < QLEN; ++t) {
            const int idx = q[t];
            if (idx != 0) {
                const float4 a = *(const float4*)(A + (size_t)idx * DIM + d);
                acc.x += a.x; acc.y += a.y; acc.z += a.z; acc.w += a.w;
            }
        }
        *(float4*)(u + (size_t)b * DIM + d) = acc;
        return;
    }
    const unsigned pass = blk / (BS * STORY);
    const unsigned bs   = blk - pass * (BS * STORY);
    const float* table = A + (size_t)pass * TBL;
    const int*   cw    = ctx + bs * SENT;

    float4 m  = make_float4(0.f, 0.f, 0.f, 0.f);
    float4 cc = make_float4(0.f, 0.f, 0.f, 0.f);
    const float invD = 1.0f / (float)DIM;
    #pragma unroll 8
    for (int w = 0; w < SENT; ++w) {
        const int idx = cw[w];
        if (idx == 0) continue;
        const float4 a = *(const float4*)(table + (size_t)idx * DIM + d);
        const float aw = 1.0f - (float)(w + 1) * (1.0f / (float)SENT);
        const float bw = 1.0f - (float)(2 * (w + 1)) * (1.0f / (float)SENT);
        m.x = fmaf(a.x, aw - bw * (float)(d + 1) * invD, m.x);
        m.y = fmaf(a.y, aw - bw * (float)(d + 2) * invD, m.y);
        m.z = fmaf(a.z, aw - bw * (float)(d + 3) * invD, m.z);
        m.w = fmaf(a.w, aw - bw * (float)(d + 4) * invD, m.w);
        cc.x += a.x; cc.y += a.y; cc.z += a.z; cc.w += a.w;
    }
    if (pass < 3) *(float4*)(mw + (size_t)pass * SZ + (size_t)bs * DIM + d) = m;
    if (pass > 0) *(float4*)(c + (size_t)(pass - 1) * SZ + (size_t)bs * DIM + d) = cc;
}

// ---------------------------------------------------------------------------
// All 3 hops fused; u lives in LDS across hops. grid: BS blocks x 512 thr.
__global__ __launch_bounds__(512) void k_hops(const float* __restrict__ mw,
                                              const float* __restrict__ c,
                                              const float* __restrict__ T_A,
                                              const float* __restrict__ u_g,
                                              ushort*      __restrict__ ubf) {
    const int b    = blockIdx.x;
    const int tid  = threadIdx.x;
    const int wave = tid >> 6;
    const int lane = tid & 63;
    __shared__ float su[DIM];        // current u
    __shared__ float sw[64];         // scores -> softmax weights
    __shared__ float up[8][DIM];     // per-wave partial u-updates

    su[tid] = u_g[(size_t)b * DIM + tid];
    __syncthreads();

    for (int h = 0; h < NUM_HOP; ++h) {
        const float* mwh = mw + (size_t)h * SZ + (size_t)b * STORY * DIM;
        const float* ch  = c  + (size_t)h * SZ + (size_t)b * STORY * DIM;

        // Phase A: scores[s] = dot(mw[s]+T_A[s], u)
        const float4 u0 = *(const float4*)(&su[lane * 8]);
        const float4 u1 = *(const float4*)(&su[lane * 8 + 4]);
        for (int s = wave; s < STORY; s += 8) {
            const float* mrow = mwh + (size_t)s * DIM + lane * 8;
            const float* trow = T_A + (size_t)s * DIM + lane * 8;
            const float4 m0 = *(const float4*)(mrow);
            const float4 m1 = *(const float4*)(mrow + 4);
            const float4 t0 = *(const float4*)(trow);
            const float4 t1 = *(const float4*)(trow + 4);
            float p = (m0.x + t0.x) * u0.x + (m0.y + t0.y) * u0.y +
                      (m0.z + t0.z) * u0.z + (m0.w + t0.w) * u0.w +
                      (m1.x + t1.x) * u1.x + (m1.y + t1.y) * u1.y +
                      (m1.z + t1.z) * u1.z + (m1.w + t1.w) * u1.w;
            for (int off = 32; off; off >>= 1) p += __shfl_down(p, off);
            if (lane == 0) sw[s] = p;
        }
        __syncthreads();

        // Phase B: softmax over STORY (first wave)
        if (tid < 64) {
            const float v = (tid < STORY) ? sw[tid] : -1e30f;
            float mx = v;
            for (int off = 32; off; off >>= 1) mx = fmaxf(mx, __shfl_down(mx, off));
            mx = __shfl(mx, 0);
            const float e = (tid < STORY) ? __expf(v - mx) : 0.f;
            float sm = e;
            for (int off = 32; off; off >>= 1) sm += __shfl_down(sm, off);
            sm = __shfl(sm, 0);
            if (tid < STORY) sw[tid] = e / sm;
        }
        __syncthreads();

        // Phase C: wave w accumulates p[s]*c[s,:] for s = w, w+8, ...
        float4 a0 = make_float4(0.f, 0.f, 0.f, 0.f);
        float4 a1 = make_float4(0.f, 0.f, 0.f, 0.f);
        for (int s = wave; s < STORY; s += 8) {
            const float  w    = sw[s];
            const float* crow = ch + (size_t)s * DIM + lane * 8;
            const float4 c0 = *(const float4*)(crow);
            const float4 c1 = *(const float4*)(crow + 4);
            a0.x = fmaf(w, c0.x, a0.x); a0.y = fmaf(w, c0.y, a0.y);
            a0.z = fmaf(w, c0.z, a0.z); a0.w = fmaf(w, c0.w, a0.w);
            a1.x = fmaf(w, c1.x, a1.x); a1.y = fmaf(w, c1.y, a1.y);
            a1.z = fmaf(w, c1.z, a1.z); a1.w = fmaf(w, c1.w, a1.w);
        }
        *(float4*)(&up[wave][lane * 8])     = a0;
        *(float4*)(&up[wave][lane * 8 + 4]) = a1;
        __syncthreads();

        float add = 0.f;
        #pragma unroll
        for (int w = 0; w < 8; ++w) add += up[w][tid];
        su[tid] += add;
        __syncthreads();
    }

    ubf[(size_t)b * DIM + tid] = f2bf(su[tid]);
}

// ---------------------------------------------------------------------------
// logits = u @ A3^T via bf16 MFMA 16x16x32 (A3 read once). grid 500 x 256.
__global__ __launch_bounds__(256) void k_logits(const float*  __restrict__ A3,
                                                const ushort* __restrict__ ubf,
                                                float*        __restrict__ out) {
    __shared__ ushort Abf[64 * 128];  // 16 KB
    __shared__ ushort Ubf[64 * 128];  // 16 KB
    const int tid  = threadIdx.x;
    const int lane = tid & 63;
    const int wave = tid >> 6;
    const int i16  = lane & 15;
    const int quad = lane >> 4;
    const int row0 = blockIdx.x * 64;

    v4f acc[4];
    #pragma unroll
    for (int nt = 0; nt < 4; ++nt) acc[nt] = (v4f){0.f, 0.f, 0.f, 0.f};

    for (int ko = 0; ko < 4; ++ko) {
        __syncthreads();
        #pragma unroll
        for (int it = 0; it < 4; ++it) {
            const int i = it * 256 + tid;
            const int r = i >> 4, g = i & 15;
            const float* src = A3 + ((size_t)(row0 + r)) * DIM + ko * 128 + g * 8;
            const float4 f0 = *(const float4*)(src);
            const float4 f1 = *(const float4*)(src + 4);
            union { ushort h[8]; uint4 q; } pk;
            pk.h[0] = f2bf(f0.x); pk.h[1] = f2bf(f0.y);
            pk.h[2] = f2bf(f0.z); pk.h[3] = f2bf(f0.w);
            pk.h[4] = f2bf(f1.x); pk.h[5] = f2bf(f1.y);
            pk.h[6] = f2bf(f1.z); pk.h[7] = f2bf(f1.w);
            *(uint4*)(&Abf[r * 128 + ((g ^ (r & 7)) * 8)]) = pk.q;
        }
        #pragma unroll
        for (int it = 0; it < 4; ++it) {
            const int i = it * 256 + tid;
            const int n = i >> 4, g = i & 15;
            const uint4 v = *(const uint4*)(ubf + (size_t)n * DIM + ko * 128 + g * 8);
            *(uint4*)(&Ubf[n * 128 + ((g ^ (n & 7)) * 8)]) = v;
        }
        __syncthreads();

        const int arow = wave * 16 + i16;
        #pragma unroll
        for (int ki = 0; ki < 4; ++ki) {
            const int ga = ki * 4 + quad;
            const v8s a = *(const v8s*)(&Abf[arow * 128 + ((ga ^ (arow & 7)) * 8)]);
            #pragma unroll
            for (int nt = 0; nt < 4; ++nt) {
                const int n = nt * 16 + i16;
                const v8s bb = *(const v8s*)(&Ubf[n * 128 + ((ga ^ (n & 7)) * 8)]);
                acc[nt] = __builtin_amdgcn_mfma_f32_16x16x32_bf16(a, bb, acc[nt], 0, 0, 0);
            }
        }
    }

    const int vbase = row0 + wave * 16 + quad * 4;
    #pragma unroll
    for (int nt = 0; nt < 4; ++nt) {
        const int bcol = nt * 16 + i16;
        #pragma unroll
        for (int r = 0; r < 4; ++r)
            out[(size_t)bcol * VOCAB + vbase + r] = acc[nt][r];
    }
}

// ---------------------------------------------------------------------------
// in-place row softmax over VOCAB; row cached in registers, exp computed once.
// grid: BS blocks x 1024 threads (each owns 31 or 32 elements).
__global__ __launch_bounds__(1024) void k_vsm(float* __restrict__ out) {
    const int b   = blockIdx.x;
    const int tid = threadIdx.x;
    float* row = out + (size_t)b * VOCAB;
    __shared__ float red[16];
    __shared__ float bc;

    float x[32];
    #pragma unroll
    for (int k = 0; k < 31; ++k) x[k] = row[tid + k * 1024];
    const bool extra = (tid < VOCAB - 31 * 1024);
    x[31] = extra ? row[tid + 31 * 1024] : -1e30f;

    // block max
    float mx = -1e30f;
    #pragma unroll
    for (int k = 0; k < 32; ++k) mx = fmaxf(mx, x[k]);
    for (int off = 32; off; off >>= 1) mx = fmaxf(mx, __shfl_down(mx, off));
    if ((tid & 63) == 0) red[tid >> 6] = mx;
    __syncthreads();
    if (tid < 64) {
        float v = (tid < 16) ? red[tid] : -1e30f;
        for (int off = 8; off; off >>= 1) v = fmaxf(v, __shfl_down(v, off));
        if (tid == 0) bc = v;
    }
    __syncthreads();
    mx = bc;
    __syncthreads();

    // exp once, block sum
    float sum = 0.f;
    #pragma unroll
    for (int k = 0; k < 32; ++k) { x[k] = __expf(x[k] - mx); sum += x[k]; }
    if (!extra) sum -= x[31];
    for (int off = 32; off; off >>= 1) sum += __shfl_down(sum, off);
    if ((tid & 63) == 0) red[tid >> 6] = sum;
    __syncthreads();
    if (tid < 64) {
        float v = (tid < 16) ? red[tid] : 0.f;
        for (int off = 8; off; off >>= 1) v += __shfl_down(v, off);
        if (tid == 0) bc = v;
    }
    __syncthreads();
    const float inv = 1.0f / bc;

    #pragma unroll
    for (int k = 0; k < 31; ++k) row[tid + k * 1024] = x[k] * inv;
    if (extra) row[tid + 31 * 1024] = x[31] * inv;
}

// ---------------------------------------------------------------------------
extern "C" void kernel_launch(void* const* d_in, const int* in_sizes, int n_in,
                              void* d_out, int out_size, void* d_ws, size_t ws_size,
                              hipStream_t stream) {
    const int*   ctx   = (const int*)d_in[0];    // (BS, STORY, SENT)
    const int*   query = (const int*)d_in[1];    // (BS, QLEN)
    const float* A     = (const float*)d_in[2];  // (4, VOCAB, DIM)
    const float* T_A   = (const float*)d_in[3];  // (1, MEM, DIM)
    float* out = (float*)d_out;                  // (BS, VOCAB)

    float*  u   = (float*)d_ws;                        // BS*DIM floats
    ushort* ubf = (ushort*)(u + (size_t)BS * DIM);     // BS*DIM bf16
    float*  mw  = (float*)(ubf + (size_t)BS * DIM);    // 3 * SZ
    float*  c   = mw + 3 * SZ;                         // 3 * SZ

    k_gather<<<4 * BS * STORY + BS, 128, 0, stream>>>(A, ctx, query, mw, c, u);
    k_hops  <<<BS, 512, 0, stream>>>(mw, c, T_A, u, ubf);
    k_logits<<<VOCAB / 64, 256, 0, stream>>>(A + 3 * TBL, ubf, out);
    k_vsm   <<<BS, 1024, 0, stream>>>(out);
}